// Round 13
// baseline (97.943 us; speedup 1.0000x reference)
//
#include <hip/hip_runtime.h>
#include <hip/hip_bf16.h>

typedef __bf16 bf16x8 __attribute__((ext_vector_type(8)));
typedef _Float16 f16x8 __attribute__((ext_vector_type(8)));
typedef _Float16 f16x2 __attribute__((ext_vector_type(2)));
typedef float f32x4 __attribute__((ext_vector_type(4)));

#define B_DIM 16
#define L_DIM 1024
#define H_DIM 4
#define HC 128
#define TI 64
#define WPITCH 136   // bf16 elems; 272B rows, 16B-aligned
#define PROJ_BLOCKS 256

// ---------------------------------------------------------------------------
// Kernel 1 (heterogeneous prep): blocks 0..255 = projection (64 rows each),
// blocks 256..2303 = adjacency bit-pack (proven R7 pattern, 8 rows each).
// Proj blocks dispatch FIRST so every CU overlaps the 64MB adj stream with
// proj's MFMA compute instead of running the two phases serially.
// ---------------------------------------------------------------------------
__global__ __launch_bounds__(256) void prep_kernel(
    const float* __restrict__ x, const float* __restrict__ W,
    const float* __restrict__ bias, const float* __restrict__ att_src,
    const float* __restrict__ att_dst, const int* __restrict__ adj,
    _Float16* __restrict__ xpT, _Float16* __restrict__ E1h,
    _Float16* __restrict__ E2h, float* __restrict__ Rr,
    unsigned* __restrict__ mask_g)
{
  __shared__ __align__(16) __bf16 Wlds[128 * WPITCH];   // 34.8 KB
  __shared__ __align__(16) __bf16 xh[64 * WPITCH];      // 17.4 KB
  __shared__ __align__(16) __bf16 xl[64 * WPITCH];      // 17.4 KB
  const int bid = blockIdx.x;
  const int t = threadIdx.x;
  const int wv = t >> 6, lane = t & 63;

  if (bid >= PROJ_BLOCKS) {
    // ---- mask role: rows (bid-256)*8 + wv*2 + {0,1} ----
    const int row0 = (bid - PROJ_BLOCKS) * 8 + wv * 2;
    const int* base = adj + (size_t)row0 * L_DIM;
    int4 av[8];
#pragma unroll
    for (int c = 0; c < 4; ++c) {
      av[c]     = *reinterpret_cast<const int4*>(base + c * 256 + lane * 4);
      av[c + 4] = *reinterpret_cast<const int4*>(base + 1024 + c * 256 + lane * 4);
    }
#pragma unroll
    for (int r = 0; r < 2; ++r) {
      const int row = row0 + r;
      const int i = row & (L_DIM - 1);
#pragma unroll
      for (int c = 0; c < 4; ++c) {
        const int4 u = av[r * 4 + c];
        unsigned b4 = (unsigned)u.x | ((unsigned)u.y << 1) |
                      ((unsigned)u.z << 2) | ((unsigned)u.w << 3);
        unsigned p;
        p = __shfl_xor(b4, 1);
        unsigned b8  = (lane & 1) ? (p | (b4 << 4))   : (b4 | (p << 4));
        p = __shfl_xor(b8, 2);
        unsigned b16 = (lane & 2) ? (p | (b8 << 8))   : (b8 | (p << 8));
        p = __shfl_xor(b16, 4);
        unsigned b32 = (lane & 4) ? (p | (b16 << 16)) : (b16 | (p << 16));
        const int widx = c * 8 + (lane >> 3);
        if ((i >> 5) == widx) b32 |= (1u << (i & 31));
        if ((lane & 7) == 0) mask_g[(size_t)row * 32 + widx] = b32;
      }
    }
    return;
  }

  // ---- proj role: rows bid*64 .. +63; wave w owns rows w*16..+15 ----
  const int r0 = bid * 64;
#pragma unroll
  for (int p = 0; p < 8; ++p) {
    const int idx = p * 2048 + t * 8;
    const int n = idx >> 7, k = idx & 127;
    const f32x4 a = *reinterpret_cast<const f32x4*>(W + idx);
    const f32x4 b = *reinterpret_cast<const f32x4*>(W + idx + 4);
    bf16x8 v;
#pragma unroll
    for (int e = 0; e < 4; ++e) { v[e] = (__bf16)a[e]; v[e + 4] = (__bf16)b[e]; }
    *reinterpret_cast<bf16x8*>(&Wlds[n * WPITCH + k]) = v;
  }
#pragma unroll
  for (int p = 0; p < 4; ++p) {
    const int idx = p * 2048 + t * 8;
    const int r = idx >> 7, k = idx & 127;
    const float* xp_ = x + (size_t)(r0 + r) * 128 + k;
    const f32x4 a = *reinterpret_cast<const f32x4*>(xp_);
    const f32x4 b = *reinterpret_cast<const f32x4*>(xp_ + 4);
    bf16x8 vh, vl;
#pragma unroll
    for (int e = 0; e < 4; ++e) {
      const float fa = a[e], fb = b[e];
      vh[e] = (__bf16)fa;          vh[e + 4] = (__bf16)fb;
      vl[e] = (__bf16)(fa - (float)vh[e]);
      vl[e + 4] = (__bf16)(fb - (float)vh[e + 4]);
    }
    *reinterpret_cast<bf16x8*>(&xh[r * WPITCH + k]) = vh;
    *reinterpret_cast<bf16x8*>(&xl[r * WPITCH + k]) = vl;
  }
  __syncthreads();

  const int rr = lane & 15;
  const int g8 = (lane >> 4) * 8;
  f32x4 acc[8] = {};
#pragma unroll
  for (int kk = 0; kk < 4; ++kk) {
    const int ko = kk * 32 + g8;
    const bf16x8 bh = *reinterpret_cast<const bf16x8*>(&xh[(wv * 16 + rr) * WPITCH + ko]);
    const bf16x8 bl = *reinterpret_cast<const bf16x8*>(&xl[(wv * 16 + rr) * WPITCH + ko]);
#pragma unroll
    for (int nc = 0; nc < 8; ++nc) {
      const bf16x8 af = *reinterpret_cast<const bf16x8*>(&Wlds[(nc * 16 + rr) * WPITCH + ko]);
      acc[nc] = __builtin_amdgcn_mfma_f32_16x16x32_bf16(af, bh, acc[nc], 0, 0, 0);
      acc[nc] = __builtin_amdgcn_mfma_f32_16x16x32_bf16(af, bl, acc[nc], 0, 0, 0);
    }
  }

  const int q4 = (lane >> 4) * 4;
  const int grow = r0 + wv * 16 + rr;
  const int bb = grow >> 10;
  const int lg = grow & 1023;
  float asum[4] = {0.f, 0.f, 0.f, 0.f};
  float adsum[4] = {0.f, 0.f, 0.f, 0.f};
#pragma unroll
  for (int nc = 0; nc < 8; ++nc) {
    const int n0 = nc * 16 + q4;
    const f32x4 bv = *reinterpret_cast<const f32x4*>(bias + n0);
    const f32x4 sv = *reinterpret_cast<const f32x4*>(att_src + n0);
    const f32x4 dv = *reinterpret_cast<const f32x4*>(att_dst + n0);
    const int h = nc >> 1;
#pragma unroll
    for (int reg = 0; reg < 4; ++reg) {
      const float v = acc[nc][reg] + bv[reg];
      const int n = n0 + reg;
      xpT[((size_t)bb * 128 + n) * 1024 + lg] = (_Float16)v;
      asum[h]  = fmaf(v, sv[reg], asum[h]);
      adsum[h] = fmaf(v, dv[reg], adsum[h]);
    }
  }
#pragma unroll
  for (int h = 0; h < 4; ++h) {
    asum[h]  += __shfl_xor(asum[h], 16);
    asum[h]  += __shfl_xor(asum[h], 32);
    adsum[h] += __shfl_xor(adsum[h], 16);
    adsum[h] += __shfl_xor(adsum[h], 32);
  }
  if ((lane >> 4) == 0) {
#pragma unroll
    for (int h = 0; h < 4; ++h) {
      const size_t o = ((size_t)bb * 4 + h) * 1024 + lg;
      E1h[o] = (_Float16)(16.0f * __expf(asum[h]));
      E2h[o] = (_Float16)__expf(0.2f * asum[h]);
      Rr[o]  = 16.0f * __expf(-0.8f * adsum[h]);
    }
  }
}

// ---------------------------------------------------------------------------
// Kernel 2 (flash attn, TI=64, 1024 threads = 16 waves = 4 heads x 4 j-qtrs):
//   Wave (h, jq): 8 iters of K=32 over j in [jq*256, +256), FOUR 16-row
//   A-fragments per iter from one e1/e2/xpT stream. 4 waves/SIMD (R11's
//   proven latency-hiding) WITH TI=64 amortization (R12's lever) combined.
//   Combine: zero-init LDS comb (stride-13 pad), all waves atomicAdd their
//   partials, jq=0 waves normalize + store. comb OVERLAYS e/msk post-barrier.
// ---------------------------------------------------------------------------
__global__ __launch_bounds__(1024, 4) void gat_attn_kernel(
    const unsigned* __restrict__ mask_g, const _Float16* __restrict__ xpT,
    const _Float16* __restrict__ E1h, const _Float16* __restrict__ E2h,
    const float* __restrict__ Rr, float* __restrict__ out)
{
  // phase 1: e1u[4][512] | e2u[4][512] | msk[64][176]  (27.6 KB)
  // phase 2 (after barrier): comb[4][4][64][13] floats  (53.2 KB)
  __shared__ __align__(16) char smem[53248];
  unsigned* e1u = reinterpret_cast<unsigned*>(smem);
  unsigned* e2u = reinterpret_cast<unsigned*>(smem + 8192);
  unsigned char* msk = reinterpret_cast<unsigned char*>(smem + 16384);
  float* comb = reinterpret_cast<float*>(smem);

  const int wg  = blockIdx.x;     // 256 blocks
  const int xcd = wg & 7;
  const int idx = wg >> 3;
  const int b   = xcd * 2 + (idx & 1);
  const int i0  = (idx >> 1) * TI;

  const int t = threadIdx.x;
  const int wv = t >> 6;        // 0..15
  const int lane = t & 63;
  const int h  = wv >> 2;       // head
  const int jq = wv & 3;        // j-quarter

  // ---- staging ----
  {
    const int r = t >> 4, sg = t & 15;   // 64 rows x 16 segs of 8B
    const uint2 m = *reinterpret_cast<const uint2*>(
        mask_g + ((size_t)b * L_DIM + i0 + r) * 32 + sg * 2);
    *reinterpret_cast<uint2*>(&msk[r * 176 + sg * 8]) = m;
  }
  {
    const int sh = t >> 8;          // head for staging
    const int off = (t & 255) * 4;  // f16 elems
    const _Float16* p1 = E1h + ((size_t)(b * H_DIM + sh)) * L_DIM + off;
    const _Float16* p2 = E2h + ((size_t)(b * H_DIM + sh)) * L_DIM + off;
    *reinterpret_cast<uint2*>(&e1u[sh * 512 + (off >> 1)]) = *reinterpret_cast<const uint2*>(p1);
    *reinterpret_cast<uint2*>(&e2u[sh * 512 + (off >> 1)]) = *reinterpret_cast<const uint2*>(p2);
  }
  __syncthreads();

  const int ln15 = lane & 15;
  const int kh = lane >> 4;
  const int jb = kh * 8;
  const int base = jq * 256;
  const float* RrB = Rr + ((size_t)(b * H_DIM + h)) * L_DIM + i0 + ln15;
  f16x2 R2g[4];
#pragma unroll
  for (int g = 0; g < 4; ++g) {
    const _Float16 rh = (_Float16)RrB[g * 16];
    R2g[g][0] = rh; R2g[g][1] = rh;
  }
  const _Float16* xb0 = xpT + ((size_t)(b * 128 + h * 32 + ln15)) * 1024 + base;
  const _Float16* xb1 = xb0 + 16 * 1024;

  f32x4 acc0[4] = {}, acc1[4] = {}, accS[4] = {};
  f16x8 ones16;
#pragma unroll
  for (int e = 0; e < 8; ++e) ones16[e] = (_Float16)1.0f;

  // 2-deep xpT ring
  uint4 pf0[2], pf1[2];
#pragma unroll
  for (int s = 0; s < 2; ++s) {
    pf0[s] = *reinterpret_cast<const uint4*>(xb0 + s * 32 + jb);
    pf1[s] = *reinterpret_cast<const uint4*>(xb1 + s * 32 + jb);
  }
  // e-read 1-iter pipeline
  uint4 u1c = *reinterpret_cast<const uint4*>(&e1u[h * 512 + ((base + jb) >> 1)]);
  uint4 u2c = *reinterpret_cast<const uint4*>(&e2u[h * 512 + ((base + jb) >> 1)]);

#pragma unroll 4
  for (int kr = 0; kr < 256; kr += 32) {
    const int k0 = base + kr;
    const int wb = jq * 32 + ((kr >> 5) << 2);   // mask word byte offset
    unsigned mb[4];
#pragma unroll
    for (int g = 0; g < 4; ++g) {
      const unsigned w32 = *reinterpret_cast<const unsigned*>(
          &msk[(g * 16 + ln15) * 176 + wb]);
      mb[g] = (w32 >> (kh * 8)) & 0xffu;
    }

    const int kn = (((k0 + 32) & 1023) + jb) >> 1;
    const uint4 u1n = *reinterpret_cast<const uint4*>(&e1u[h * 512 + kn]);
    const uint4 u2n = *reinterpret_cast<const uint4*>(&e2u[h * 512 + kn]);

    const int sl = (kr >> 5) & 1;
    const uint4 bb0 = pf0[sl];
    const uint4 bb1 = pf1[sl];
    pf0[sl] = *reinterpret_cast<const uint4*>(xb0 + kr + 64 + jb);  // over-read safe (ws)
    pf1[sl] = *reinterpret_cast<const uint4*>(xb1 + kr + 64 + jb);

    const unsigned uu1[4] = {u1c.x, u1c.y, u1c.z, u1c.w};
    const unsigned uu2[4] = {u2c.x, u2c.y, u2c.z, u2c.w};
    unsigned rg[4][4];
#pragma unroll
    for (int q = 0; q < 4; ++q) {
      f16x2 a, ee;
      __builtin_memcpy(&a,  &uu1[q], 4);
      __builtin_memcpy(&ee, &uu2[q], 4);
#pragma unroll
      for (int g = 0; g < 4; ++g) {
        const f16x2 pr = ee * R2g[g];                         // v_pk_mul_f16
        const f16x2 mx = __builtin_elementwise_max(a, pr);    // v_pk_max_f16
        unsigned mu;
        __builtin_memcpy(&mu, &mx, 4);
        const unsigned mlo = (mb[g] & (1u << (2 * q)))     ? 0xFFFFu : 0u;
        const unsigned mhi = (mb[g] & (1u << (2 * q + 1))) ? 0xFFFF0000u : 0u;
        rg[g][q] = mu & (mlo | mhi);
      }
    }
    f16x8 b0h, b1h;
    __builtin_memcpy(&b0h, &bb0, 16);
    __builtin_memcpy(&b1h, &bb1, 16);
#pragma unroll
    for (int g = 0; g < 4; ++g) {
      const uint4 afu = {rg[g][0], rg[g][1], rg[g][2], rg[g][3]};
      f16x8 af;
      __builtin_memcpy(&af, &afu, 16);
      acc0[g] = __builtin_amdgcn_mfma_f32_16x16x32_f16(af, b0h, acc0[g], 0, 0, 0);
      acc1[g] = __builtin_amdgcn_mfma_f32_16x16x32_f16(af, b1h, acc1[g], 0, 0, 0);
      accS[g] = __builtin_amdgcn_mfma_f32_16x16x32_f16(af, ones16, accS[g], 0, 0, 0);
    }
    u1c = u1n; u2c = u2n;
  }

  // ---- combine: zero comb, atomicAdd partials, jq=0 normalizes+stores ----
  __syncthreads();                       // e/msk reads complete
  for (int i = t; i < 4 * 4 * 64 * 13; i += 1024) comb[i] = 0.0f;
  __syncthreads();
#pragma unroll
  for (int g = 0; g < 4; ++g) {
    float* cp = &comb[((h * 4 + g) * 64 + lane) * 13];
#pragma unroll
    for (int e = 0; e < 4; ++e) {
      atomicAdd(&cp[e],     acc0[g][e]);
      atomicAdd(&cp[4 + e], acc1[g][e]);
      atomicAdd(&cp[8 + e], accS[g][e]);
    }
  }
  __syncthreads();
  if (jq == 0) {
#pragma unroll
    for (int g = 0; g < 4; ++g) {
      const float* cp = &comb[((h * 4 + g) * 64 + lane) * 13];
#pragma unroll
      for (int reg = 0; reg < 4; ++reg) {
        const float rs = 1.0f / cp[8 + reg];
        float* op = out + ((size_t)(b * L_DIM + i0 + g * 16 + kh * 4 + reg)) * HC + h * 32;
        op[ln15]      = cp[reg]     * rs;
        op[16 + ln15] = cp[4 + reg] * rs;
      }
    }
  }
}

extern "C" void kernel_launch(void* const* d_in, const int* in_sizes, int n_in,
                              void* d_out, int out_size, void* d_ws, size_t ws_size,
                              hipStream_t stream) {
  (void)in_sizes; (void)n_in; (void)out_size; (void)ws_size;
  const float* x        = (const float*)d_in[0];
  const int*   adj      = (const int*)d_in[1];
  const float* W        = (const float*)d_in[2];
  const float* bias     = (const float*)d_in[3];
  const float* att_src  = (const float*)d_in[4];
  const float* att_dst  = (const float*)d_in[5];
  float* out = (float*)d_out;

  char* ws = (char*)d_ws;
  _Float16* xpT    = (_Float16*)ws;                                    // 4 MiB
  _Float16* E1h    = (_Float16*)(ws + (size_t)4 * 1024 * 1024);        // 128 KiB
  _Float16* E2h    = (_Float16*)(ws + (size_t)4 * 1024 * 1024 + 131072);
  float*    Rr     = (float*)(ws + (size_t)4 * 1024 * 1024 + 262144);  // 256 KiB
  unsigned* mask_g = (unsigned*)(ws + (size_t)4 * 1024 * 1024 + 524288); // 2 MiB

  hipLaunchKernelGGL(prep_kernel, dim3(PROJ_BLOCKS + B_DIM * L_DIM / 8), dim3(256), 0, stream,
                     x, W, bias, att_src, att_dst, adj, xpT, E1h, E2h, Rr, mask_g);
  hipLaunchKernelGGL(gat_attn_kernel, dim3(B_DIM * L_DIM / TI), dim3(1024), 0, stream,
                     mask_g, xpT, E1h, E2h, Rr, out);
}

// Round 15
// 49.324 us; speedup vs baseline: 1.9857x; 1.9857x over previous
//
#include <hip/hip_runtime.h>
#include <hip/hip_bf16.h>

typedef __bf16 bf16x8 __attribute__((ext_vector_type(8)));
typedef _Float16 f16x8 __attribute__((ext_vector_type(8)));
typedef _Float16 f16x2 __attribute__((ext_vector_type(2)));
typedef float f32x4 __attribute__((ext_vector_type(4)));

#define B_DIM 16
#define L_DIM 1024
#define H_DIM 4
#define HC 128
#define TI 64
#define WPITCH 136   // bf16 elems; 272B rows, 16B-aligned

// ---------------------------------------------------------------------------
// Kernel 1: adjacency -> packed bitmask (proven R7/R12 pattern).
// ---------------------------------------------------------------------------
__global__ __launch_bounds__(256) void mask_pack_kernel(
    const int* __restrict__ adj, unsigned* __restrict__ mask_g)
{
  const int t = threadIdx.x;
  const int wv = t >> 6, lane = t & 63;
  const int row0 = blockIdx.x * 8 + wv * 2;
  const int* base = adj + (size_t)row0 * L_DIM;

  int4 av[8];
#pragma unroll
  for (int c = 0; c < 4; ++c) {
    av[c]     = *reinterpret_cast<const int4*>(base + c * 256 + lane * 4);
    av[c + 4] = *reinterpret_cast<const int4*>(base + 1024 + c * 256 + lane * 4);
  }

#pragma unroll
  for (int r = 0; r < 2; ++r) {
    const int row = row0 + r;
    const int i = row & (L_DIM - 1);
#pragma unroll
    for (int c = 0; c < 4; ++c) {
      const int4 u = av[r * 4 + c];
      unsigned b4 = (unsigned)u.x | ((unsigned)u.y << 1) |
                    ((unsigned)u.z << 2) | ((unsigned)u.w << 3);
      unsigned p;
      p = __shfl_xor(b4, 1);
      unsigned b8  = (lane & 1) ? (p | (b4 << 4))   : (b4 | (p << 4));
      p = __shfl_xor(b8, 2);
      unsigned b16 = (lane & 2) ? (p | (b8 << 8))   : (b8 | (p << 8));
      p = __shfl_xor(b16, 4);
      unsigned b32 = (lane & 4) ? (p | (b16 << 16)) : (b16 | (p << 16));
      const int widx = c * 8 + (lane >> 3);
      if ((i >> 5) == widx) b32 |= (1u << (i & 31));
      if ((lane & 7) == 0) mask_g[(size_t)row * 32 + widx] = b32;
    }
  }
}

// ---------------------------------------------------------------------------
// Kernel 2: projection via MFMA (proven R12). bf16 hi/lo compensated core,
// fp16 outputs, x16 pre-scale for fp16 range.
// ---------------------------------------------------------------------------
__global__ __launch_bounds__(128) void proj_kernel(
    const float* __restrict__ x, const float* __restrict__ W,
    const float* __restrict__ bias, const float* __restrict__ att_src,
    const float* __restrict__ att_dst, _Float16* __restrict__ xpT,
    _Float16* __restrict__ E1h, _Float16* __restrict__ E2h,
    float* __restrict__ Rr)
{
  __shared__ __align__(16) __bf16 Wlds[128 * WPITCH];
  __shared__ __align__(16) __bf16 xh[32 * WPITCH];
  __shared__ __align__(16) __bf16 xl[32 * WPITCH];
  const int t = threadIdx.x;
  const int w = t >> 6;
  const int lane = t & 63;
  const int r0 = blockIdx.x * 32;

#pragma unroll
  for (int p = 0; p < 16; ++p) {
    const int idx = p * 1024 + t * 8;
    const int n = idx >> 7, k = idx & 127;
    const f32x4 a = *reinterpret_cast<const f32x4*>(W + idx);
    const f32x4 b = *reinterpret_cast<const f32x4*>(W + idx + 4);
    bf16x8 v;
#pragma unroll
    for (int e = 0; e < 4; ++e) { v[e] = (__bf16)a[e]; v[e + 4] = (__bf16)b[e]; }
    *reinterpret_cast<bf16x8*>(&Wlds[n * WPITCH + k]) = v;
  }
#pragma unroll
  for (int p = 0; p < 4; ++p) {
    const int idx = p * 1024 + t * 8;
    const int r = idx >> 7, k = idx & 127;
    const float* xp_ = x + (size_t)(r0 + r) * 128 + k;
    const f32x4 a = *reinterpret_cast<const f32x4*>(xp_);
    const f32x4 b = *reinterpret_cast<const f32x4*>(xp_ + 4);
    bf16x8 vh, vl;
#pragma unroll
    for (int e = 0; e < 4; ++e) {
      const float fa = a[e], fb = b[e];
      vh[e] = (__bf16)fa;          vh[e + 4] = (__bf16)fb;
      vl[e] = (__bf16)(fa - (float)vh[e]);
      vl[e + 4] = (__bf16)(fb - (float)vh[e + 4]);
    }
    *reinterpret_cast<bf16x8*>(&xh[r * WPITCH + k]) = vh;
    *reinterpret_cast<bf16x8*>(&xl[r * WPITCH + k]) = vl;
  }
  __syncthreads();

  const int rr = lane & 15;
  const int g8 = (lane >> 4) * 8;
  f32x4 acc[8] = {};
#pragma unroll
  for (int kk = 0; kk < 4; ++kk) {
    const int ko = kk * 32 + g8;
    const bf16x8 bh = *reinterpret_cast<const bf16x8*>(&xh[(w * 16 + rr) * WPITCH + ko]);
    const bf16x8 bl = *reinterpret_cast<const bf16x8*>(&xl[(w * 16 + rr) * WPITCH + ko]);
#pragma unroll
    for (int nc = 0; nc < 8; ++nc) {
      const bf16x8 af = *reinterpret_cast<const bf16x8*>(&Wlds[(nc * 16 + rr) * WPITCH + ko]);
      acc[nc] = __builtin_amdgcn_mfma_f32_16x16x32_bf16(af, bh, acc[nc], 0, 0, 0);
      acc[nc] = __builtin_amdgcn_mfma_f32_16x16x32_bf16(af, bl, acc[nc], 0, 0, 0);
    }
  }

  const int q4 = (lane >> 4) * 4;
  const int grow = r0 + w * 16 + rr;
  const int bb = grow >> 10;
  const int lg = grow & 1023;
  float asum[4] = {0.f, 0.f, 0.f, 0.f};
  float adsum[4] = {0.f, 0.f, 0.f, 0.f};
#pragma unroll
  for (int nc = 0; nc < 8; ++nc) {
    const int n0 = nc * 16 + q4;
    const f32x4 bv = *reinterpret_cast<const f32x4*>(bias + n0);
    const f32x4 sv = *reinterpret_cast<const f32x4*>(att_src + n0);
    const f32x4 dv = *reinterpret_cast<const f32x4*>(att_dst + n0);
    const int h = nc >> 1;
#pragma unroll
    for (int reg = 0; reg < 4; ++reg) {
      const float v = acc[nc][reg] + bv[reg];
      const int n = n0 + reg;
      xpT[((size_t)bb * 128 + n) * 1024 + lg] = (_Float16)v;
      asum[h]  = fmaf(v, sv[reg], asum[h]);
      adsum[h] = fmaf(v, dv[reg], adsum[h]);
    }
  }
#pragma unroll
  for (int h = 0; h < 4; ++h) {
    asum[h]  += __shfl_xor(asum[h], 16);
    asum[h]  += __shfl_xor(asum[h], 32);
    adsum[h] += __shfl_xor(adsum[h], 16);
    adsum[h] += __shfl_xor(adsum[h], 32);
  }
  if ((lane >> 4) == 0) {
#pragma unroll
    for (int h = 0; h < 4; ++h) {
      const size_t o = ((size_t)bb * 4 + h) * 1024 + lg;
      E1h[o] = (_Float16)(16.0f * __expf(asum[h]));
      E2h[o] = (_Float16)__expf(0.2f * asum[h]);
      Rr[o]  = 16.0f * __expf(-0.8f * adsum[h]);
    }
  }
}

// ---------------------------------------------------------------------------
// Kernel 3 (flash attn, TI=64, head-pair split) — R14 with the LDS overlay
// sized CORRECTLY: comb[2][3][4][64][13] f32 = 79,872 B (R14 declared half
// of that and wrote OOB). 80KB LDS -> 2 blocks/CU = 4 waves/SIMD, matching
// the 512-block grid exactly.
// ---------------------------------------------------------------------------
__global__ __launch_bounds__(512, 4) void gat_attn_kernel(
    const unsigned* __restrict__ mask_g, const _Float16* __restrict__ xpT,
    const _Float16* __restrict__ E1h, const _Float16* __restrict__ E2h,
    const float* __restrict__ Rr, float* __restrict__ out)
{
  // phase 1: e1u[2][512] | e2u[2][512] | msk[64][176]   (19.0 KB used)
  // phase 2 (after barrier): comb[2][3][4][64][13] f32  (79,872 B)
  __shared__ __align__(16) char smem[79872];
  unsigned* e1u = reinterpret_cast<unsigned*>(smem);                   // [hh][512]
  unsigned* e2u = reinterpret_cast<unsigned*>(smem + 4096);            // [hh][512]
  unsigned char* msk = reinterpret_cast<unsigned char*>(smem + 8192);  // [64][176]
  float* comb = reinterpret_cast<float*>(smem);                        // [hh][jq-1][g][64][13]

  const int wg  = blockIdx.x;     // 512 blocks
  const int xcd = wg & 7;
  const int idx = wg >> 3;        // 0..63 per XCD
  const int b   = xcd * 2 + (idx & 1);
  const int it  = idx >> 1;       // 0..31: tile x head-pair
  const int hp  = it & 1;         // head-pair
  const int i0  = (it >> 1) * TI; // row-tile base

  const int t = threadIdx.x;
  const int wv = t >> 6;        // 0..7
  const int lane = t & 63;
  const int hh = wv >> 2;       // head within pair
  const int h  = hp * 2 + hh;   // global head
  const int jq = wv & 3;        // j-quarter

  // ---- staging ----
  {
    const int r = t >> 3, sg = t & 7;        // 64 rows x 8 segs of 16B
    const uint4 m = *reinterpret_cast<const uint4*>(
        mask_g + ((size_t)b * L_DIM + i0 + r) * 32 + sg * 4);
    *reinterpret_cast<uint4*>(&msk[r * 176 + sg * 16]) = m;
  }
  {
    const int sh = t >> 8;          // local head 0/1
    const int off = (t & 255) * 4;  // f16 elems
    const _Float16* p1 = E1h + ((size_t)(b * H_DIM + hp * 2 + sh)) * L_DIM + off;
    const _Float16* p2 = E2h + ((size_t)(b * H_DIM + hp * 2 + sh)) * L_DIM + off;
    *reinterpret_cast<uint2*>(&e1u[sh * 512 + (off >> 1)]) = *reinterpret_cast<const uint2*>(p1);
    *reinterpret_cast<uint2*>(&e2u[sh * 512 + (off >> 1)]) = *reinterpret_cast<const uint2*>(p2);
  }
  __syncthreads();

  const int ln15 = lane & 15;
  const int kh = lane >> 4;
  const int jb = kh * 8;
  const int base = jq * 256;
  const float* RrB = Rr + ((size_t)(b * H_DIM + h)) * L_DIM + i0 + ln15;
  f16x2 R2g[4];
#pragma unroll
  for (int g = 0; g < 4; ++g) {
    const _Float16 rh = (_Float16)RrB[g * 16];
    R2g[g][0] = rh; R2g[g][1] = rh;
  }
  const _Float16* xb0 = xpT + ((size_t)(b * 128 + h * 32 + ln15)) * 1024 + base;
  const _Float16* xb1 = xb0 + 16 * 1024;

  f32x4 acc0[4] = {}, acc1[4] = {}, accS[4] = {};
  f16x8 ones16;
#pragma unroll
  for (int e = 0; e < 8; ++e) ones16[e] = (_Float16)1.0f;

  // 2-deep xpT ring
  uint4 pf0[2], pf1[2];
#pragma unroll
  for (int s = 0; s < 2; ++s) {
    pf0[s] = *reinterpret_cast<const uint4*>(xb0 + s * 32 + jb);
    pf1[s] = *reinterpret_cast<const uint4*>(xb1 + s * 32 + jb);
  }
  // e-read 1-iter pipeline
  uint4 u1c = *reinterpret_cast<const uint4*>(&e1u[hh * 512 + ((base + jb) >> 1)]);
  uint4 u2c = *reinterpret_cast<const uint4*>(&e2u[hh * 512 + ((base + jb) >> 1)]);

#pragma unroll 4
  for (int kr = 0; kr < 256; kr += 32) {
    const int k0 = base + kr;
    const int wb = jq * 32 + ((kr >> 5) << 2);   // mask word byte offset
    unsigned mb[4];
#pragma unroll
    for (int g = 0; g < 4; ++g) {
      const unsigned w32 = *reinterpret_cast<const unsigned*>(
          &msk[(g * 16 + ln15) * 176 + wb]);
      mb[g] = (w32 >> (kh * 8)) & 0xffu;
    }

    // next-iter e-reads (wrap keeps address in-bounds; value unused at end)
    const int kn = (((k0 + 32) & 1023) + jb) >> 1;
    const uint4 u1n = *reinterpret_cast<const uint4*>(&e1u[hh * 512 + kn]);
    const uint4 u2n = *reinterpret_cast<const uint4*>(&e2u[hh * 512 + kn]);

    const int sl = (kr >> 5) & 1;
    const uint4 bb0 = pf0[sl];
    const uint4 bb1 = pf1[sl];
    pf0[sl] = *reinterpret_cast<const uint4*>(xb0 + kr + 64 + jb);  // over-read safe (ws)
    pf1[sl] = *reinterpret_cast<const uint4*>(xb1 + kr + 64 + jb);

    const unsigned uu1[4] = {u1c.x, u1c.y, u1c.z, u1c.w};
    const unsigned uu2[4] = {u2c.x, u2c.y, u2c.z, u2c.w};
    unsigned rg[4][4];
#pragma unroll
    for (int q = 0; q < 4; ++q) {
      f16x2 a, ee;
      __builtin_memcpy(&a,  &uu1[q], 4);
      __builtin_memcpy(&ee, &uu2[q], 4);
#pragma unroll
      for (int g = 0; g < 4; ++g) {
        const f16x2 pr = ee * R2g[g];                         // v_pk_mul_f16
        const f16x2 mx = __builtin_elementwise_max(a, pr);    // v_pk_max_f16
        unsigned mu;
        __builtin_memcpy(&mu, &mx, 4);
        const unsigned mlo = (mb[g] & (1u << (2 * q)))     ? 0xFFFFu : 0u;
        const unsigned mhi = (mb[g] & (1u << (2 * q + 1))) ? 0xFFFF0000u : 0u;
        rg[g][q] = mu & (mlo | mhi);
      }
    }
    f16x8 b0h, b1h;
    __builtin_memcpy(&b0h, &bb0, 16);
    __builtin_memcpy(&b1h, &bb1, 16);
#pragma unroll
    for (int g = 0; g < 4; ++g) {
      const uint4 afu = {rg[g][0], rg[g][1], rg[g][2], rg[g][3]};
      f16x8 af;
      __builtin_memcpy(&af, &afu, 16);
      acc0[g] = __builtin_amdgcn_mfma_f32_16x16x32_f16(af, b0h, acc0[g], 0, 0, 0);
      acc1[g] = __builtin_amdgcn_mfma_f32_16x16x32_f16(af, b1h, acc1[g], 0, 0, 0);
      accS[g] = __builtin_amdgcn_mfma_f32_16x16x32_f16(af, ones16, accS[g], 0, 0, 0);
    }
    u1c = u1n; u2c = u2n;
  }

  // ---- combine: jq!=0 write partial slots; jq=0 sums + normalizes ----
  __syncthreads();                       // e/msk reads complete before overlay
  if (jq != 0) {
#pragma unroll
    for (int g = 0; g < 4; ++g) {
      float* cp = &comb[(((hh * 3 + (jq - 1)) * 4 + g) * 64 + lane) * 13];
#pragma unroll
      for (int e = 0; e < 4; ++e) {
        cp[e]     = acc0[g][e];
        cp[4 + e] = acc1[g][e];
        cp[8 + e] = accS[g][e];
      }
    }
  }
  __syncthreads();
  if (jq == 0) {
#pragma unroll
    for (int g = 0; g < 4; ++g) {
      f32x4 s0 = acc0[g], s1 = acc1[g], sS = accS[g];
#pragma unroll
      for (int p = 0; p < 3; ++p) {
        const float* cp = &comb[(((hh * 3 + p) * 4 + g) * 64 + lane) * 13];
#pragma unroll
        for (int e = 0; e < 4; ++e) {
          s0[e] += cp[e];
          s1[e] += cp[4 + e];
          sS[e] += cp[8 + e];
        }
      }
#pragma unroll
      for (int reg = 0; reg < 4; ++reg) {
        const float rs = 1.0f / sS[reg];
        float* op = out + ((size_t)(b * L_DIM + i0 + g * 16 + kh * 4 + reg)) * HC + h * 32;
        op[ln15]      = s0[reg] * rs;
        op[16 + ln15] = s1[reg] * rs;
      }
    }
  }
}

extern "C" void kernel_launch(void* const* d_in, const int* in_sizes, int n_in,
                              void* d_out, int out_size, void* d_ws, size_t ws_size,
                              hipStream_t stream) {
  (void)in_sizes; (void)n_in; (void)out_size; (void)ws_size;
  const float* x        = (const float*)d_in[0];
  const int*   adj      = (const int*)d_in[1];
  const float* W        = (const float*)d_in[2];
  const float* bias     = (const float*)d_in[3];
  const float* att_src  = (const float*)d_in[4];
  const float* att_dst  = (const float*)d_in[5];
  float* out = (float*)d_out;

  char* ws = (char*)d_ws;
  _Float16* xpT    = (_Float16*)ws;                                    // 4 MiB
  _Float16* E1h    = (_Float16*)(ws + (size_t)4 * 1024 * 1024);        // 128 KiB
  _Float16* E2h    = (_Float16*)(ws + (size_t)4 * 1024 * 1024 + 131072);
  float*    Rr     = (float*)(ws + (size_t)4 * 1024 * 1024 + 262144);  // 256 KiB
  unsigned* mask_g = (unsigned*)(ws + (size_t)4 * 1024 * 1024 + 524288); // 2 MiB

  hipLaunchKernelGGL(mask_pack_kernel, dim3(B_DIM * L_DIM / 8), dim3(256), 0, stream,
                     adj, mask_g);
  hipLaunchKernelGGL(proj_kernel, dim3(B_DIM * L_DIM / 32), dim3(128), 0, stream,
                     x, W, bias, att_src, att_dst, xpT, E1h, E2h, Rr);
  hipLaunchKernelGGL(gat_attn_kernel, dim3(2 * B_DIM * L_DIM / TI), dim3(512), 0, stream,
                     mask_g, xpT, E1h, E2h, Rr, out);
}

// Round 16
// 38.828 us; speedup vs baseline: 2.5225x; 1.2703x over previous
//
#include <hip/hip_runtime.h>
#include <hip/hip_bf16.h>

typedef __bf16 bf16x8 __attribute__((ext_vector_type(8)));
typedef _Float16 f16x8 __attribute__((ext_vector_type(8)));
typedef _Float16 f16x2 __attribute__((ext_vector_type(2)));
typedef float f32x4 __attribute__((ext_vector_type(4)));

#define B_DIM 16
#define L_DIM 1024
#define H_DIM 4
#define HC 128
#define TI 64
#define WPITCH 136   // bf16 elems; 272B rows, 16B-aligned
#define PROJ_BLOCKS 256

// ---------------------------------------------------------------------------
// Kernel 1 (heterogeneous prep, R13-proven): blocks 0..255 = projection
// (64 rows each), blocks 256..2303 = adjacency bit-pack (proven pattern,
// 8 rows each). Proj blocks dispatch FIRST so CUs overlap the 64MB adj
// stream with proj's MFMA compute; kills one launch gap.
// ---------------------------------------------------------------------------
__global__ __launch_bounds__(256) void prep_kernel(
    const float* __restrict__ x, const float* __restrict__ W,
    const float* __restrict__ bias, const float* __restrict__ att_src,
    const float* __restrict__ att_dst, const int* __restrict__ adj,
    _Float16* __restrict__ xpT, _Float16* __restrict__ E1h,
    _Float16* __restrict__ E2h, float* __restrict__ Rr,
    unsigned* __restrict__ mask_g)
{
  __shared__ __align__(16) __bf16 Wlds[128 * WPITCH];   // 34.8 KB
  __shared__ __align__(16) __bf16 xh[64 * WPITCH];      // 17.4 KB
  __shared__ __align__(16) __bf16 xl[64 * WPITCH];      // 17.4 KB
  const int bid = blockIdx.x;
  const int t = threadIdx.x;
  const int wv = t >> 6, lane = t & 63;

  if (bid >= PROJ_BLOCKS) {
    // ---- mask role: rows (bid-256)*8 + wv*2 + {0,1} ----
    const int row0 = (bid - PROJ_BLOCKS) * 8 + wv * 2;
    const int* base = adj + (size_t)row0 * L_DIM;
    int4 av[8];
#pragma unroll
    for (int c = 0; c < 4; ++c) {
      av[c]     = *reinterpret_cast<const int4*>(base + c * 256 + lane * 4);
      av[c + 4] = *reinterpret_cast<const int4*>(base + 1024 + c * 256 + lane * 4);
    }
#pragma unroll
    for (int r = 0; r < 2; ++r) {
      const int row = row0 + r;
      const int i = row & (L_DIM - 1);
#pragma unroll
      for (int c = 0; c < 4; ++c) {
        const int4 u = av[r * 4 + c];
        unsigned b4 = (unsigned)u.x | ((unsigned)u.y << 1) |
                      ((unsigned)u.z << 2) | ((unsigned)u.w << 3);
        unsigned p;
        p = __shfl_xor(b4, 1);
        unsigned b8  = (lane & 1) ? (p | (b4 << 4))   : (b4 | (p << 4));
        p = __shfl_xor(b8, 2);
        unsigned b16 = (lane & 2) ? (p | (b8 << 8))   : (b8 | (p << 8));
        p = __shfl_xor(b16, 4);
        unsigned b32 = (lane & 4) ? (p | (b16 << 16)) : (b16 | (p << 16));
        const int widx = c * 8 + (lane >> 3);
        if ((i >> 5) == widx) b32 |= (1u << (i & 31));
        if ((lane & 7) == 0) mask_g[(size_t)row * 32 + widx] = b32;
      }
    }
    return;
  }

  // ---- proj role: rows bid*64 .. +63; wave w owns rows w*16..+15 ----
  const int r0 = bid * 64;
#pragma unroll
  for (int p = 0; p < 8; ++p) {
    const int idx = p * 2048 + t * 8;
    const int n = idx >> 7, k = idx & 127;
    const f32x4 a = *reinterpret_cast<const f32x4*>(W + idx);
    const f32x4 b = *reinterpret_cast<const f32x4*>(W + idx + 4);
    bf16x8 v;
#pragma unroll
    for (int e = 0; e < 4; ++e) { v[e] = (__bf16)a[e]; v[e + 4] = (__bf16)b[e]; }
    *reinterpret_cast<bf16x8*>(&Wlds[n * WPITCH + k]) = v;
  }
#pragma unroll
  for (int p = 0; p < 4; ++p) {
    const int idx = p * 2048 + t * 8;
    const int r = idx >> 7, k = idx & 127;
    const float* xp_ = x + (size_t)(r0 + r) * 128 + k;
    const f32x4 a = *reinterpret_cast<const f32x4*>(xp_);
    const f32x4 b = *reinterpret_cast<const f32x4*>(xp_ + 4);
    bf16x8 vh, vl;
#pragma unroll
    for (int e = 0; e < 4; ++e) {
      const float fa = a[e], fb = b[e];
      vh[e] = (__bf16)fa;          vh[e + 4] = (__bf16)fb;
      vl[e] = (__bf16)(fa - (float)vh[e]);
      vl[e + 4] = (__bf16)(fb - (float)vh[e + 4]);
    }
    *reinterpret_cast<bf16x8*>(&xh[r * WPITCH + k]) = vh;
    *reinterpret_cast<bf16x8*>(&xl[r * WPITCH + k]) = vl;
  }
  __syncthreads();

  const int rr = lane & 15;
  const int g8 = (lane >> 4) * 8;
  f32x4 acc[8] = {};
#pragma unroll
  for (int kk = 0; kk < 4; ++kk) {
    const int ko = kk * 32 + g8;
    const bf16x8 bh = *reinterpret_cast<const bf16x8*>(&xh[(wv * 16 + rr) * WPITCH + ko]);
    const bf16x8 bl = *reinterpret_cast<const bf16x8*>(&xl[(wv * 16 + rr) * WPITCH + ko]);
#pragma unroll
    for (int nc = 0; nc < 8; ++nc) {
      const bf16x8 af = *reinterpret_cast<const bf16x8*>(&Wlds[(nc * 16 + rr) * WPITCH + ko]);
      acc[nc] = __builtin_amdgcn_mfma_f32_16x16x32_bf16(af, bh, acc[nc], 0, 0, 0);
      acc[nc] = __builtin_amdgcn_mfma_f32_16x16x32_bf16(af, bl, acc[nc], 0, 0, 0);
    }
  }

  const int q4 = (lane >> 4) * 4;
  const int grow = r0 + wv * 16 + rr;
  const int bb = grow >> 10;
  const int lg = grow & 1023;
  float asum[4] = {0.f, 0.f, 0.f, 0.f};
  float adsum[4] = {0.f, 0.f, 0.f, 0.f};
#pragma unroll
  for (int nc = 0; nc < 8; ++nc) {
    const int n0 = nc * 16 + q4;
    const f32x4 bv = *reinterpret_cast<const f32x4*>(bias + n0);
    const f32x4 sv = *reinterpret_cast<const f32x4*>(att_src + n0);
    const f32x4 dv = *reinterpret_cast<const f32x4*>(att_dst + n0);
    const int h = nc >> 1;
#pragma unroll
    for (int reg = 0; reg < 4; ++reg) {
      const float v = acc[nc][reg] + bv[reg];
      const int n = n0 + reg;
      xpT[((size_t)bb * 128 + n) * 1024 + lg] = (_Float16)v;
      asum[h]  = fmaf(v, sv[reg], asum[h]);
      adsum[h] = fmaf(v, dv[reg], adsum[h]);
    }
  }
#pragma unroll
  for (int h = 0; h < 4; ++h) {
    asum[h]  += __shfl_xor(asum[h], 16);
    asum[h]  += __shfl_xor(asum[h], 32);
    adsum[h] += __shfl_xor(adsum[h], 16);
    adsum[h] += __shfl_xor(adsum[h], 32);
  }
  if ((lane >> 4) == 0) {
#pragma unroll
    for (int h = 0; h < 4; ++h) {
      const size_t o = ((size_t)bb * 4 + h) * 1024 + lg;
      E1h[o] = (_Float16)(16.0f * __expf(asum[h]));
      E2h[o] = (_Float16)__expf(0.2f * asum[h]);
      Rr[o]  = 16.0f * __expf(-0.8f * adsum[h]);
    }
  }
}

// ---------------------------------------------------------------------------
// Kernel 2 (flash attn) — R12-EXACT (the best measured config, ~21us):
//   512 thr = 8 waves = 4 heads x 2 j-halves; TI=64; 16 iters of K=32;
//   FOUR 16-row A-fragments per iter from one e1/e2/xpT stream; 12 f16
//   MFMAs/iter; combine overlays e/msk LDS after a barrier.
// ---------------------------------------------------------------------------
__global__ __launch_bounds__(512, 4) void gat_attn_kernel(
    const unsigned* __restrict__ mask_g, const _Float16* __restrict__ xpT,
    const _Float16* __restrict__ E1h, const _Float16* __restrict__ E2h,
    const float* __restrict__ Rr, float* __restrict__ out)
{
  // phase 1: e1u[4][512] | e2u[4][512] | msk[64][176]  (27.6 KB)
  // phase 2 (after barrier): comb[4][4][64][13] floats  (53,248 B exact)
  __shared__ __align__(16) char smem[53248];
  unsigned* e1u = reinterpret_cast<unsigned*>(smem);
  unsigned* e2u = reinterpret_cast<unsigned*>(smem + 8192);
  unsigned char* msk = reinterpret_cast<unsigned char*>(smem + 16384);
  float* comb = reinterpret_cast<float*>(smem);

  const int wg  = blockIdx.x;     // 256 blocks
  const int xcd = wg & 7;
  const int idx = wg >> 3;
  const int b   = xcd * 2 + (idx & 1);
  const int i0  = (idx >> 1) * TI;

  const int t = threadIdx.x;
  const int wv = t >> 6;        // 0..7
  const int lane = t & 63;
  const int h  = wv >> 1;       // head
  const int jh = wv & 1;        // j-half

  // ---- staging ----
  {
    const int r = t >> 3, sg = t & 7;        // 64 rows x 8 segs of 16B
    const uint4 m = *reinterpret_cast<const uint4*>(
        mask_g + ((size_t)b * L_DIM + i0 + r) * 32 + sg * 4);
    *reinterpret_cast<uint4*>(&msk[r * 176 + sg * 16]) = m;
  }
  {
    const int sh = t >> 7;          // head for staging
    const int off = (t & 127) * 8;  // element offset within head slice
    const _Float16* p1 = E1h + ((size_t)(b * H_DIM + sh)) * L_DIM + off;
    const _Float16* p2 = E2h + ((size_t)(b * H_DIM + sh)) * L_DIM + off;
    *reinterpret_cast<uint4*>(&e1u[sh * 512 + (off >> 1)]) = *reinterpret_cast<const uint4*>(p1);
    *reinterpret_cast<uint4*>(&e2u[sh * 512 + (off >> 1)]) = *reinterpret_cast<const uint4*>(p2);
  }
  __syncthreads();

  const int ln15 = lane & 15;
  const int kh = lane >> 4;
  const int jb = kh * 8;
  const int base = jh * 512;
  const float* RrB = Rr + ((size_t)(b * H_DIM + h)) * L_DIM + i0 + ln15;
  f16x2 R2g[4];
#pragma unroll
  for (int g = 0; g < 4; ++g) {
    const _Float16 rh = (_Float16)RrB[g * 16];
    R2g[g][0] = rh; R2g[g][1] = rh;
  }
  const _Float16* xb0 = xpT + ((size_t)(b * 128 + h * 32 + ln15)) * 1024 + base;
  const _Float16* xb1 = xb0 + 16 * 1024;

  f32x4 acc0[4] = {}, acc1[4] = {}, accS[4] = {};
  f16x8 ones16;
#pragma unroll
  for (int e = 0; e < 8; ++e) ones16[e] = (_Float16)1.0f;

  // 2-deep xpT ring
  uint4 pf0[2], pf1[2];
#pragma unroll
  for (int s = 0; s < 2; ++s) {
    pf0[s] = *reinterpret_cast<const uint4*>(xb0 + s * 32 + jb);
    pf1[s] = *reinterpret_cast<const uint4*>(xb1 + s * 32 + jb);
  }
  // e-read 1-iter pipeline
  uint4 u1c = *reinterpret_cast<const uint4*>(&e1u[h * 512 + ((base + jb) >> 1)]);
  uint4 u2c = *reinterpret_cast<const uint4*>(&e2u[h * 512 + ((base + jb) >> 1)]);

#pragma unroll 4
  for (int kr = 0; kr < 512; kr += 32) {
    const int k0 = base + kr;
    // per-group mask words from LDS (broadcast across kh, 2-way bank: free)
    const int wb = jh * 64 + ((kr >> 5) << 2);
    unsigned mb[4];
#pragma unroll
    for (int g = 0; g < 4; ++g) {
      const unsigned w32 = *reinterpret_cast<const unsigned*>(
          &msk[(g * 16 + ln15) * 176 + wb]);
      mb[g] = (w32 >> (kh * 8)) & 0xffu;
    }

    // next-iter e-reads (wrap keeps address in-bounds; value unused at end)
    const int kn = (((k0 + 32) & 1023) + jb) >> 1;
    const uint4 u1n = *reinterpret_cast<const uint4*>(&e1u[h * 512 + kn]);
    const uint4 u2n = *reinterpret_cast<const uint4*>(&e2u[h * 512 + kn]);

    const int sl = (kr >> 5) & 1;
    const uint4 bb0 = pf0[sl];
    const uint4 bb1 = pf1[sl];
    pf0[sl] = *reinterpret_cast<const uint4*>(xb0 + kr + 64 + jb);  // over-read safe (ws)
    pf1[sl] = *reinterpret_cast<const uint4*>(xb1 + kr + 64 + jb);

    const unsigned uu1[4] = {u1c.x, u1c.y, u1c.z, u1c.w};
    const unsigned uu2[4] = {u2c.x, u2c.y, u2c.z, u2c.w};
    unsigned rg[4][4];
#pragma unroll
    for (int q = 0; q < 4; ++q) {
      f16x2 a, ee;
      __builtin_memcpy(&a,  &uu1[q], 4);
      __builtin_memcpy(&ee, &uu2[q], 4);
#pragma unroll
      for (int g = 0; g < 4; ++g) {
        const f16x2 pr = ee * R2g[g];                         // v_pk_mul_f16
        const f16x2 mx = __builtin_elementwise_max(a, pr);    // v_pk_max_f16
        unsigned mu;
        __builtin_memcpy(&mu, &mx, 4);
        const unsigned mlo = (mb[g] & (1u << (2 * q)))     ? 0xFFFFu : 0u;
        const unsigned mhi = (mb[g] & (1u << (2 * q + 1))) ? 0xFFFF0000u : 0u;
        rg[g][q] = mu & (mlo | mhi);
      }
    }
    f16x8 b0h, b1h;
    __builtin_memcpy(&b0h, &bb0, 16);
    __builtin_memcpy(&b1h, &bb1, 16);
#pragma unroll
    for (int g = 0; g < 4; ++g) {
      const uint4 afu = {rg[g][0], rg[g][1], rg[g][2], rg[g][3]};
      f16x8 af;
      __builtin_memcpy(&af, &afu, 16);
      acc0[g] = __builtin_amdgcn_mfma_f32_16x16x32_f16(af, b0h, acc0[g], 0, 0, 0);
      acc1[g] = __builtin_amdgcn_mfma_f32_16x16x32_f16(af, b1h, acc1[g], 0, 0, 0);
      accS[g] = __builtin_amdgcn_mfma_f32_16x16x32_f16(af, ones16, accS[g], 0, 0, 0);
    }
    u1c = u1n; u2c = u2n;
  }

  // ---- combine: jh=1 dumps partials; jh=0 adds, normalizes, stores ----
  __syncthreads();                       // e/msk reads complete before overlay
  if (jh == 1) {
#pragma unroll
    for (int g = 0; g < 4; ++g) {
      float* cp = &comb[((h * 4 + g) * 64 + lane) * 13];
#pragma unroll
      for (int e = 0; e < 4; ++e) {
        cp[e]     = acc0[g][e];
        cp[4 + e] = acc1[g][e];
        cp[8 + e] = accS[g][e];
      }
    }
  }
  __syncthreads();
  if (jh == 0) {
#pragma unroll
    for (int g = 0; g < 4; ++g) {
      const float* cp = &comb[((h * 4 + g) * 64 + lane) * 13];
#pragma unroll
      for (int reg = 0; reg < 4; ++reg) {
        const float s = accS[g][reg] + cp[8 + reg];
        const float rs = 1.0f / s;
        float* op = out + ((size_t)(b * L_DIM + i0 + g * 16 + kh * 4 + reg)) * HC + h * 32;
        op[ln15]      = (acc0[g][reg] + cp[reg])     * rs;
        op[16 + ln15] = (acc1[g][reg] + cp[4 + reg]) * rs;
      }
    }
  }
}

extern "C" void kernel_launch(void* const* d_in, const int* in_sizes, int n_in,
                              void* d_out, int out_size, void* d_ws, size_t ws_size,
                              hipStream_t stream) {
  (void)in_sizes; (void)n_in; (void)out_size; (void)ws_size;
  const float* x        = (const float*)d_in[0];
  const int*   adj      = (const int*)d_in[1];
  const float* W        = (const float*)d_in[2];
  const float* bias     = (const float*)d_in[3];
  const float* att_src  = (const float*)d_in[4];
  const float* att_dst  = (const float*)d_in[5];
  float* out = (float*)d_out;

  char* ws = (char*)d_ws;
  _Float16* xpT    = (_Float16*)ws;                                    // 4 MiB
  _Float16* E1h    = (_Float16*)(ws + (size_t)4 * 1024 * 1024);        // 128 KiB
  _Float16* E2h    = (_Float16*)(ws + (size_t)4 * 1024 * 1024 + 131072);
  float*    Rr     = (float*)(ws + (size_t)4 * 1024 * 1024 + 262144);  // 256 KiB
  unsigned* mask_g = (unsigned*)(ws + (size_t)4 * 1024 * 1024 + 524288); // 2 MiB

  hipLaunchKernelGGL(prep_kernel, dim3(PROJ_BLOCKS + B_DIM * L_DIM / 8), dim3(256), 0, stream,
                     x, W, bias, att_src, att_dst, adj, xpT, E1h, E2h, Rr, mask_g);
  hipLaunchKernelGGL(gat_attn_kernel, dim3(B_DIM * L_DIM / TI), dim3(512), 0, stream,
                     mask_g, xpT, E1h, E2h, Rr, out);
}

// Round 17
// 37.585 us; speedup vs baseline: 2.6059x; 1.0331x over previous
//
#include <hip/hip_runtime.h>
#include <hip/hip_bf16.h>

typedef __bf16 bf16x8 __attribute__((ext_vector_type(8)));
typedef _Float16 f16x8 __attribute__((ext_vector_type(8)));
typedef _Float16 f16x2 __attribute__((ext_vector_type(2)));
typedef float f32x4 __attribute__((ext_vector_type(4)));

#define B_DIM 16
#define L_DIM 1024
#define H_DIM 4
#define HC 128
#define TI 64
#define WPITCH 136   // bf16 elems; 272B rows, 16B-aligned
#define PROJ_BLOCKS 256

// ---------------------------------------------------------------------------
// Kernel 1 (heterogeneous prep, R16-proven): blocks 0..255 = projection
// (64 rows each), blocks 256..2303 = adjacency bit-pack (8 rows each).
// Proj blocks dispatch FIRST so CUs overlap the 64MB adj stream with proj's
// MFMA compute; kills one launch gap.
// ---------------------------------------------------------------------------
__global__ __launch_bounds__(256) void prep_kernel(
    const float* __restrict__ x, const float* __restrict__ W,
    const float* __restrict__ bias, const float* __restrict__ att_src,
    const float* __restrict__ att_dst, const int* __restrict__ adj,
    _Float16* __restrict__ xpT, _Float16* __restrict__ E1h,
    _Float16* __restrict__ E2h, float* __restrict__ Rr,
    unsigned* __restrict__ mask_g)
{
  __shared__ __align__(16) __bf16 Wlds[128 * WPITCH];   // 34.8 KB
  __shared__ __align__(16) __bf16 xh[64 * WPITCH];      // 17.4 KB
  __shared__ __align__(16) __bf16 xl[64 * WPITCH];      // 17.4 KB
  const int bid = blockIdx.x;
  const int t = threadIdx.x;
  const int wv = t >> 6, lane = t & 63;

  if (bid >= PROJ_BLOCKS) {
    // ---- mask role: rows (bid-256)*8 + wv*2 + {0,1} ----
    const int row0 = (bid - PROJ_BLOCKS) * 8 + wv * 2;
    const int* base = adj + (size_t)row0 * L_DIM;
    int4 av[8];
#pragma unroll
    for (int c = 0; c < 4; ++c) {
      av[c]     = *reinterpret_cast<const int4*>(base + c * 256 + lane * 4);
      av[c + 4] = *reinterpret_cast<const int4*>(base + 1024 + c * 256 + lane * 4);
    }
#pragma unroll
    for (int r = 0; r < 2; ++r) {
      const int row = row0 + r;
      const int i = row & (L_DIM - 1);
#pragma unroll
      for (int c = 0; c < 4; ++c) {
        const int4 u = av[r * 4 + c];
        unsigned b4 = (unsigned)u.x | ((unsigned)u.y << 1) |
                      ((unsigned)u.z << 2) | ((unsigned)u.w << 3);
        unsigned p;
        p = __shfl_xor(b4, 1);
        unsigned b8  = (lane & 1) ? (p | (b4 << 4))   : (b4 | (p << 4));
        p = __shfl_xor(b8, 2);
        unsigned b16 = (lane & 2) ? (p | (b8 << 8))   : (b8 | (p << 8));
        p = __shfl_xor(b16, 4);
        unsigned b32 = (lane & 4) ? (p | (b16 << 16)) : (b16 | (p << 16));
        const int widx = c * 8 + (lane >> 3);
        if ((i >> 5) == widx) b32 |= (1u << (i & 31));
        if ((lane & 7) == 0) mask_g[(size_t)row * 32 + widx] = b32;
      }
    }
    return;
  }

  // ---- proj role: rows bid*64 .. +63; wave w owns rows w*16..+15 ----
  const int r0 = bid * 64;
#pragma unroll
  for (int p = 0; p < 8; ++p) {
    const int idx = p * 2048 + t * 8;
    const int n = idx >> 7, k = idx & 127;
    const f32x4 a = *reinterpret_cast<const f32x4*>(W + idx);
    const f32x4 b = *reinterpret_cast<const f32x4*>(W + idx + 4);
    bf16x8 v;
#pragma unroll
    for (int e = 0; e < 4; ++e) { v[e] = (__bf16)a[e]; v[e + 4] = (__bf16)b[e]; }
    *reinterpret_cast<bf16x8*>(&Wlds[n * WPITCH + k]) = v;
  }
#pragma unroll
  for (int p = 0; p < 4; ++p) {
    const int idx = p * 2048 + t * 8;
    const int r = idx >> 7, k = idx & 127;
    const float* xp_ = x + (size_t)(r0 + r) * 128 + k;
    const f32x4 a = *reinterpret_cast<const f32x4*>(xp_);
    const f32x4 b = *reinterpret_cast<const f32x4*>(xp_ + 4);
    bf16x8 vh, vl;
#pragma unroll
    for (int e = 0; e < 4; ++e) {
      const float fa = a[e], fb = b[e];
      vh[e] = (__bf16)fa;          vh[e + 4] = (__bf16)fb;
      vl[e] = (__bf16)(fa - (float)vh[e]);
      vl[e + 4] = (__bf16)(fb - (float)vh[e + 4]);
    }
    *reinterpret_cast<bf16x8*>(&xh[r * WPITCH + k]) = vh;
    *reinterpret_cast<bf16x8*>(&xl[r * WPITCH + k]) = vl;
  }
  __syncthreads();

  const int rr = lane & 15;
  const int g8 = (lane >> 4) * 8;
  f32x4 acc[8] = {};
#pragma unroll
  for (int kk = 0; kk < 4; ++kk) {
    const int ko = kk * 32 + g8;
    const bf16x8 bh = *reinterpret_cast<const bf16x8*>(&xh[(wv * 16 + rr) * WPITCH + ko]);
    const bf16x8 bl = *reinterpret_cast<const bf16x8*>(&xl[(wv * 16 + rr) * WPITCH + ko]);
#pragma unroll
    for (int nc = 0; nc < 8; ++nc) {
      const bf16x8 af = *reinterpret_cast<const bf16x8*>(&Wlds[(nc * 16 + rr) * WPITCH + ko]);
      acc[nc] = __builtin_amdgcn_mfma_f32_16x16x32_bf16(af, bh, acc[nc], 0, 0, 0);
      acc[nc] = __builtin_amdgcn_mfma_f32_16x16x32_bf16(af, bl, acc[nc], 0, 0, 0);
    }
  }

  const int q4 = (lane >> 4) * 4;
  const int grow = r0 + wv * 16 + rr;
  const int bb = grow >> 10;
  const int lg = grow & 1023;
  float asum[4] = {0.f, 0.f, 0.f, 0.f};
  float adsum[4] = {0.f, 0.f, 0.f, 0.f};
#pragma unroll
  for (int nc = 0; nc < 8; ++nc) {
    const int n0 = nc * 16 + q4;
    const f32x4 bv = *reinterpret_cast<const f32x4*>(bias + n0);
    const f32x4 sv = *reinterpret_cast<const f32x4*>(att_src + n0);
    const f32x4 dv = *reinterpret_cast<const f32x4*>(att_dst + n0);
    const int h = nc >> 1;
#pragma unroll
    for (int reg = 0; reg < 4; ++reg) {
      const float v = acc[nc][reg] + bv[reg];
      const int n = n0 + reg;
      xpT[((size_t)bb * 128 + n) * 1024 + lg] = (_Float16)v;
      asum[h]  = fmaf(v, sv[reg], asum[h]);
      adsum[h] = fmaf(v, dv[reg], adsum[h]);
    }
  }
#pragma unroll
  for (int h = 0; h < 4; ++h) {
    asum[h]  += __shfl_xor(asum[h], 16);
    asum[h]  += __shfl_xor(asum[h], 32);
    adsum[h] += __shfl_xor(adsum[h], 16);
    adsum[h] += __shfl_xor(adsum[h], 32);
  }
  if ((lane >> 4) == 0) {
#pragma unroll
    for (int h = 0; h < 4; ++h) {
      const size_t o = ((size_t)bb * 4 + h) * 1024 + lg;
      E1h[o] = (_Float16)(16.0f * __expf(asum[h]));
      E2h[o] = (_Float16)__expf(0.2f * asum[h]);
      Rr[o]  = 16.0f * __expf(-0.8f * adsum[h]);
    }
  }
}

// ---------------------------------------------------------------------------
// Kernel 2 (flash attn, R12 shape + deepened pipelines):
//   512 thr = 8 waves = 4 heads x 2 j-halves; TI=64; 16 iters of K=32.
//   NEW vs R12: launch_bounds(512,2) -> 256-reg budget (grid=1 block/CU
//   regardless); xpT ring 4-deep (covers L2); e1/e2 ring 2-deep (covers
//   LDS); mask as 4x ds_read_b128 per 4-iter group held in regs (4x fewer
//   LDS ops). Attacks the measured ~6x latency exposure at 2 waves/SIMD.
// ---------------------------------------------------------------------------
__global__ __launch_bounds__(512, 2) void gat_attn_kernel(
    const unsigned* __restrict__ mask_g, const _Float16* __restrict__ xpT,
    const _Float16* __restrict__ E1h, const _Float16* __restrict__ E2h,
    const float* __restrict__ Rr, float* __restrict__ out)
{
  // phase 1: e1u[4][512] | e2u[4][512] | msk[64][176]  (27.6 KB)
  // phase 2 (after barrier): comb[4][4][64][13] floats  (53,248 B exact)
  __shared__ __align__(16) char smem[53248];
  unsigned* e1u = reinterpret_cast<unsigned*>(smem);
  unsigned* e2u = reinterpret_cast<unsigned*>(smem + 8192);
  unsigned char* msk = reinterpret_cast<unsigned char*>(smem + 16384);
  float* comb = reinterpret_cast<float*>(smem);

  const int wg  = blockIdx.x;     // 256 blocks
  const int xcd = wg & 7;
  const int idx = wg >> 3;
  const int b   = xcd * 2 + (idx & 1);
  const int i0  = (idx >> 1) * TI;

  const int t = threadIdx.x;
  const int wv = t >> 6;        // 0..7
  const int lane = t & 63;
  const int h  = wv >> 1;       // head
  const int jh = wv & 1;        // j-half

  // ---- staging ----
  {
    const int r = t >> 3, sg = t & 7;        // 64 rows x 8 segs of 16B
    const uint4 m = *reinterpret_cast<const uint4*>(
        mask_g + ((size_t)b * L_DIM + i0 + r) * 32 + sg * 4);
    *reinterpret_cast<uint4*>(&msk[r * 176 + sg * 16]) = m;
  }
  {
    const int sh = t >> 7;          // head for staging
    const int off = (t & 127) * 8;  // element offset within head slice
    const _Float16* p1 = E1h + ((size_t)(b * H_DIM + sh)) * L_DIM + off;
    const _Float16* p2 = E2h + ((size_t)(b * H_DIM + sh)) * L_DIM + off;
    *reinterpret_cast<uint4*>(&e1u[sh * 512 + (off >> 1)]) = *reinterpret_cast<const uint4*>(p1);
    *reinterpret_cast<uint4*>(&e2u[sh * 512 + (off >> 1)]) = *reinterpret_cast<const uint4*>(p2);
  }
  __syncthreads();

  const int ln15 = lane & 15;
  const int kh = lane >> 4;
  const int jb = kh * 8;
  const int base = jh * 512;
  const float* RrB = Rr + ((size_t)(b * H_DIM + h)) * L_DIM + i0 + ln15;
  f16x2 R2g[4];
#pragma unroll
  for (int g = 0; g < 4; ++g) {
    const _Float16 rh = (_Float16)RrB[g * 16];
    R2g[g][0] = rh; R2g[g][1] = rh;
  }
  const _Float16* xb0 = xpT + ((size_t)(b * 128 + h * 32 + ln15)) * 1024 + base;
  const _Float16* xb1 = xb0 + 16 * 1024;

  f32x4 acc0[4] = {}, acc1[4] = {}, accS[4] = {};
  f16x8 ones16;
#pragma unroll
  for (int e = 0; e < 8; ++e) ones16[e] = (_Float16)1.0f;

  // 4-deep xpT ring (prefetch 128 j ahead; over-reads stay inside ws)
  uint4 pf0[4], pf1[4];
#pragma unroll
  for (int s = 0; s < 4; ++s) {
    pf0[s] = *reinterpret_cast<const uint4*>(xb0 + s * 32 + jb);
    pf1[s] = *reinterpret_cast<const uint4*>(xb1 + s * 32 + jb);
  }
  // 2-deep e-read ring (prefetch 64 j ahead; wrapped tail loads unused)
  uint4 u1r[2], u2r[2];
#pragma unroll
  for (int s = 0; s < 2; ++s) {
    const int ke = (base + s * 32 + jb) >> 1;
    u1r[s] = *reinterpret_cast<const uint4*>(&e1u[h * 512 + ke]);
    u2r[s] = *reinterpret_cast<const uint4*>(&e2u[h * 512 + ke]);
  }
  uint4 mwc[4];   // per-group mask words, refreshed every 4 iters (128 j)

#pragma unroll 4
  for (int kr = 0; kr < 512; kr += 32) {
    const int tm = (kr >> 5) & 3;
    if (tm == 0) {
#pragma unroll
      for (int g = 0; g < 4; ++g)
        mwc[g] = *reinterpret_cast<const uint4*>(
            &msk[(g * 16 + ln15) * 176 + jh * 64 + (kr >> 7) * 16]);
    }
    unsigned mb[4];
#pragma unroll
    for (int g = 0; g < 4; ++g) {
      const unsigned w32 = (tm == 0) ? mwc[g].x : (tm == 1) ? mwc[g].y
                         : (tm == 2) ? mwc[g].z : mwc[g].w;
      mb[g] = (w32 >> (kh * 8)) & 0xffu;
    }

    // consume e-ring slot, refill 2 iters ahead (wrap keeps addr in-bounds)
    const int sl2 = (kr >> 5) & 1;
    const uint4 u1c = u1r[sl2];
    const uint4 u2c = u2r[sl2];
    const int kn = (((base + kr + 64) & 1023) + jb) >> 1;
    u1r[sl2] = *reinterpret_cast<const uint4*>(&e1u[h * 512 + kn]);
    u2r[sl2] = *reinterpret_cast<const uint4*>(&e2u[h * 512 + kn]);

    // consume xpT ring slot, refill 4 iters ahead (over-read lands in ws)
    const int sl = (kr >> 5) & 3;
    const uint4 bb0 = pf0[sl];
    const uint4 bb1 = pf1[sl];
    pf0[sl] = *reinterpret_cast<const uint4*>(xb0 + kr + 128 + jb);
    pf1[sl] = *reinterpret_cast<const uint4*>(xb1 + kr + 128 + jb);

    const unsigned uu1[4] = {u1c.x, u1c.y, u1c.z, u1c.w};
    const unsigned uu2[4] = {u2c.x, u2c.y, u2c.z, u2c.w};
    unsigned rg[4][4];
#pragma unroll
    for (int q = 0; q < 4; ++q) {
      f16x2 a, ee;
      __builtin_memcpy(&a,  &uu1[q], 4);
      __builtin_memcpy(&ee, &uu2[q], 4);
#pragma unroll
      for (int g = 0; g < 4; ++g) {
        const f16x2 pr = ee * R2g[g];                         // v_pk_mul_f16
        const f16x2 mx = __builtin_elementwise_max(a, pr);    // v_pk_max_f16
        unsigned mu;
        __builtin_memcpy(&mu, &mx, 4);
        const unsigned mlo = (mb[g] & (1u << (2 * q)))     ? 0xFFFFu : 0u;
        const unsigned mhi = (mb[g] & (1u << (2 * q + 1))) ? 0xFFFF0000u : 0u;
        rg[g][q] = mu & (mlo | mhi);
      }
    }
    f16x8 b0h, b1h;
    __builtin_memcpy(&b0h, &bb0, 16);
    __builtin_memcpy(&b1h, &bb1, 16);
#pragma unroll
    for (int g = 0; g < 4; ++g) {
      const uint4 afu = {rg[g][0], rg[g][1], rg[g][2], rg[g][3]};
      f16x8 af;
      __builtin_memcpy(&af, &afu, 16);
      acc0[g] = __builtin_amdgcn_mfma_f32_16x16x32_f16(af, b0h, acc0[g], 0, 0, 0);
      acc1[g] = __builtin_amdgcn_mfma_f32_16x16x32_f16(af, b1h, acc1[g], 0, 0, 0);
      accS[g] = __builtin_amdgcn_mfma_f32_16x16x32_f16(af, ones16, accS[g], 0, 0, 0);
    }
  }

  // ---- combine: jh=1 dumps partials; jh=0 adds, normalizes, stores ----
  __syncthreads();                       // e/msk reads complete before overlay
  if (jh == 1) {
#pragma unroll
    for (int g = 0; g < 4; ++g) {
      float* cp = &comb[((h * 4 + g) * 64 + lane) * 13];
#pragma unroll
      for (int e = 0; e < 4; ++e) {
        cp[e]     = acc0[g][e];
        cp[4 + e] = acc1[g][e];
        cp[8 + e] = accS[g][e];
      }
    }
  }
  __syncthreads();
  if (jh == 0) {
#pragma unroll
    for (int g = 0; g < 4; ++g) {
      const float* cp = &comb[((h * 4 + g) * 64 + lane) * 13];
#pragma unroll
      for (int reg = 0; reg < 4; ++reg) {
        const float s = accS[g][reg] + cp[8 + reg];
        const float rs = 1.0f / s;
        float* op = out + ((size_t)(b * L_DIM + i0 + g * 16 + kh * 4 + reg)) * HC + h * 32;
        op[ln15]      = (acc0[g][reg] + cp[reg])     * rs;
        op[16 + ln15] = (acc1[g][reg] + cp[4 + reg]) * rs;
      }
    }
  }
}

extern "C" void kernel_launch(void* const* d_in, const int* in_sizes, int n_in,
                              void* d_out, int out_size, void* d_ws, size_t ws_size,
                              hipStream_t stream) {
  (void)in_sizes; (void)n_in; (void)out_size; (void)ws_size;
  const float* x        = (const float*)d_in[0];
  const int*   adj      = (const int*)d_in[1];
  const float* W        = (const float*)d_in[2];
  const float* bias     = (const float*)d_in[3];
  const float* att_src  = (const float*)d_in[4];
  const float* att_dst  = (const float*)d_in[5];
  float* out = (float*)d_out;

  char* ws = (char*)d_ws;
  _Float16* xpT    = (_Float16*)ws;                                    // 4 MiB
  _Float16* E1h    = (_Float16*)(ws + (size_t)4 * 1024 * 1024);        // 128 KiB
  _Float16* E2h    = (_Float16*)(ws + (size_t)4 * 1024 * 1024 + 131072);
  float*    Rr     = (float*)(ws + (size_t)4 * 1024 * 1024 + 262144);  // 256 KiB
  unsigned* mask_g = (unsigned*)(ws + (size_t)4 * 1024 * 1024 + 524288); // 2 MiB

  hipLaunchKernelGGL(prep_kernel, dim3(PROJ_BLOCKS + B_DIM * L_DIM / 8), dim3(256), 0, stream,
                     x, W, bias, att_src, att_dst, adj, xpT, E1h, E2h, Rr, mask_g);
  hipLaunchKernelGGL(gat_attn_kernel, dim3(B_DIM * L_DIM / TI), dim3(512), 0, stream,
                     mask_g, xpT, E1h, E2h, Rr, out);
}